// Round 4
// baseline (183.720 us; speedup 1.0000x reference)
//
#include <hip/hip_runtime.h>

// One-level separable wavelet filterbank (maxflat), periodic extension.
// x: [8,3,1024,1024] f32 -> out: [4, 8,3,512,512] f32 (LL, LH, HL, HH)
//
// Round 4: barrier-free streaming. Wave = 128 output cols x 16 output rows;
// thread = 2 output cols. Per input row: one float4 load/lane (coalesced
// 1 KB/instr), cross-lane taps via __shfl (no LDS), halo lanes patch from
// global. Column filter from a 7-deep register ring, shifted 2/output row.
// Next 2 input rows explicitly prefetched.

constexpr int H = 1024, W = 1024;
constexpr int NIMG = 24;            // 8*3
constexpr int HOUT = 512, WOUT = 512;
constexpr int CH = 16;              // output rows per wave
constexpr int NSTRIP = 4;           // 4 strips of 128 output cols
constexpr int NCHUNK = HOUT / CH;   // 32
constexpr size_t SB = (size_t)NIMG * HOUT * WOUT;   // per-subband stride

struct Raw { float4 v; float4 h4; float h1v; };

__device__ __forceinline__ Raw load_row(const float* __restrict__ imgp,
                                        int gr, int ci, int lane) {
    Raw r;
    const float* __restrict__ rowp = imgp + (size_t)gr * W;
    r.v = *(const float4*)(rowp + ci + 4 * lane);
    if (lane == 0)  r.h4  = *(const float4*)(rowp + ((ci - 4) & (W - 1)));
    if (lane == 63) r.h1v = rowp[(ci + 256) & (W - 1)];
    return r;
}

// Row filter at this thread's two output cols j0 (=a) and j0+1 (=b).
// Window cols: w0..w8 = self-4 .. self+4 where self = v.x's col (2*j0).
__device__ __forceinline__ void rowfilt(const Raw& r, int lane,
                                        float& rLa, float& rHa,
                                        float& rLb, float& rHb) {
    const float h0c[5] = {0.125f, 0.35355339059327373f, 1.25f,
                          0.35355339059327373f, 0.125f};
    const float h1c[7] = {0.025888347648318447f,  0.07322330470336313f,
                          -0.06878156646177083f, -0.8535533905932737f,
                          -0.06878156646177083f,  0.07322330470336313f,
                          0.025888347648318447f};
    float4 vm1;
    vm1.x = __shfl_up(r.v.x, 1);
    vm1.y = __shfl_up(r.v.y, 1);
    vm1.z = __shfl_up(r.v.z, 1);
    vm1.w = __shfl_up(r.v.w, 1);
    float vp1 = __shfl_down(r.v.x, 1);
    if (lane == 0)  vm1 = r.h4;
    if (lane == 63) vp1 = r.h1v;
    // col a: taps cols 2j0-4..2j0+2 -> vm1.xyzw, v.xyz
    rLa = h0c[0]*vm1.z + h0c[1]*vm1.w + h0c[2]*r.v.x + h0c[3]*r.v.y + h0c[4]*r.v.z;
    rHa = h1c[0]*vm1.x + h1c[1]*vm1.y + h1c[2]*vm1.z + h1c[3]*vm1.w
        + h1c[4]*r.v.x + h1c[5]*r.v.y + h1c[6]*r.v.z;
    // col b: taps cols 2j0-2..2j0+4 -> vm1.zw, v.xyzw, vp1
    rLb = h0c[0]*r.v.x + h0c[1]*r.v.y + h0c[2]*r.v.z + h0c[3]*r.v.w + h0c[4]*vp1;
    rHb = h1c[0]*vm1.z + h1c[1]*vm1.w + h1c[2]*r.v.x + h1c[3]*r.v.y
        + h1c[4]*r.v.z + h1c[5]*r.v.w + h1c[6]*vp1;
}

__global__ __launch_bounds__(256)
void wfb_kernel(const float* __restrict__ x, float* __restrict__ out) {
    const float h0c[5] = {0.125f, 0.35355339059327373f, 1.25f,
                          0.35355339059327373f, 0.125f};
    const float h1c[7] = {0.025888347648318447f,  0.07322330470336313f,
                          -0.06878156646177083f, -0.8535533905932737f,
                          -0.06878156646177083f,  0.07322330470336313f,
                          0.025888347648318447f};

    const int tid  = threadIdx.x;
    const int lane = tid & 63;
    const int gwid = blockIdx.x * 4 + (tid >> 6);
    const int img   = gwid >> 7;          // 128 waves per image
    const int rem   = gwid & 127;
    const int chunk = rem >> 2;           // 0..31
    const int strip = rem & 3;            // 0..3

    const int i0 = chunk * CH;            // first output row
    const int ci = strip * 256;           // wave's first input col
    const int oc = strip * 128 + 2 * lane;// thread's first output col

    const float* __restrict__ xin = x + (size_t)img * H * W;
    float* __restrict__ o = out + (size_t)img * HOUT * WOUT;

    // ---- init: row-filter input rows 2*i0-4 .. 2*i0+1 into ring [0..5] ----
    float La0,La1,La2,La3,La4,La5, Ha0,Ha1,Ha2,Ha3,Ha4,Ha5;
    float Lb0,Lb1,Lb2,Lb3,Lb4,Lb5, Hb0,Hb1,Hb2,Hb3,Hb4,Hb5;
    {
        Raw t0 = load_row(xin, (2*i0 - 4) & (H-1), ci, lane);
        Raw t1 = load_row(xin, (2*i0 - 3) & (H-1), ci, lane);
        Raw t2 = load_row(xin, (2*i0 - 2) & (H-1), ci, lane);
        Raw t3 = load_row(xin, (2*i0 - 1) & (H-1), ci, lane);
        Raw t4 = load_row(xin, (2*i0 + 0) & (H-1), ci, lane);
        Raw t5 = load_row(xin, (2*i0 + 1) & (H-1), ci, lane);
        rowfilt(t0, lane, La0, Ha0, Lb0, Hb0);
        rowfilt(t1, lane, La1, Ha1, Lb1, Hb1);
        rowfilt(t2, lane, La2, Ha2, Lb2, Hb2);
        rowfilt(t3, lane, La3, Ha3, Lb3, Hb3);
        rowfilt(t4, lane, La4, Ha4, Lb4, Hb4);
        rowfilt(t5, lane, La5, Ha5, Lb5, Hb5);
    }

    Raw ra = load_row(xin, (2*i0 + 2) & (H-1), ci, lane);
    Raw rb = load_row(xin, (2*i0 + 3) & (H-1), ci, lane);

    for (int t = 0; t < CH; ++t) {
        const int gi = i0 + t;
        // prefetch next pair (wrapped; harmless past-end reads)
        Raw na = load_row(xin, (2*gi + 4) & (H-1), ci, lane);
        Raw nb = load_row(xin, (2*gi + 5) & (H-1), ci, lane);

        // ring slot 6 = input row 2*gi+2
        float La6, Ha6, Lb6, Hb6;
        rowfilt(ra, lane, La6, Ha6, Lb6, Hb6);

        // column filters: LL/HL over slots 2..6 (h0), LH/HH over 0..6 (h1)
        float LLa = h0c[0]*La2 + h0c[1]*La3 + h0c[2]*La4 + h0c[3]*La5 + h0c[4]*La6;
        float HLa = h0c[0]*Ha2 + h0c[1]*Ha3 + h0c[2]*Ha4 + h0c[3]*Ha5 + h0c[4]*Ha6;
        float LHa = h1c[0]*La0 + h1c[1]*La1 + h1c[2]*La2 + h1c[3]*La3
                  + h1c[4]*La4 + h1c[5]*La5 + h1c[6]*La6;
        float HHa = h1c[0]*Ha0 + h1c[1]*Ha1 + h1c[2]*Ha2 + h1c[3]*Ha3
                  + h1c[4]*Ha4 + h1c[5]*Ha5 + h1c[6]*Ha6;
        float LLb = h0c[0]*Lb2 + h0c[1]*Lb3 + h0c[2]*Lb4 + h0c[3]*Lb5 + h0c[4]*Lb6;
        float HLb = h0c[0]*Hb2 + h0c[1]*Hb3 + h0c[2]*Hb4 + h0c[3]*Hb5 + h0c[4]*Hb6;
        float LHb = h1c[0]*Lb0 + h1c[1]*Lb1 + h1c[2]*Lb2 + h1c[3]*Lb3
                  + h1c[4]*Lb4 + h1c[5]*Lb5 + h1c[6]*Lb6;
        float HHb = h1c[0]*Hb0 + h1c[1]*Hb1 + h1c[2]*Hb2 + h1c[3]*Hb3
                  + h1c[4]*Hb4 + h1c[5]*Hb5 + h1c[6]*Hb6;

        size_t off = (size_t)gi * WOUT + oc;
        *(float2*)(o + 0 * SB + off) = make_float2(LLa, LLb);
        *(float2*)(o + 1 * SB + off) = make_float2(LHa, LHb);
        *(float2*)(o + 2 * SB + off) = make_float2(HLa, HLb);
        *(float2*)(o + 3 * SB + off) = make_float2(HHa, HHb);

        // ring slot 5' = input row 2*gi+3; shift window down by 2
        float nLa5, nHa5, nLb5, nHb5;
        rowfilt(rb, lane, nLa5, nHa5, nLb5, nHb5);
        La0 = La2; La1 = La3; La2 = La4; La3 = La5; La4 = La6; La5 = nLa5;
        Ha0 = Ha2; Ha1 = Ha3; Ha2 = Ha4; Ha3 = Ha5; Ha4 = Ha6; Ha5 = nHa5;
        Lb0 = Lb2; Lb1 = Lb3; Lb2 = Lb4; Lb3 = Lb5; Lb4 = Lb6; Lb5 = nLb5;
        Hb0 = Hb2; Hb1 = Hb3; Hb2 = Hb4; Hb3 = Hb5; Hb4 = Hb6; Hb5 = nHb5;
        ra = na; rb = nb;
    }
}

extern "C" void kernel_launch(void* const* d_in, const int* in_sizes, int n_in,
                              void* d_out, int out_size, void* d_ws, size_t ws_size,
                              hipStream_t stream) {
    const float* x = (const float*)d_in[0];
    float* out = (float*)d_out;
    // 24 img x 32 chunks x 4 strips = 3072 waves = 768 blocks of 256
    int nblocks = NIMG * NCHUNK * NSTRIP / 4;
    wfb_kernel<<<nblocks, dim3(256), 0, stream>>>(x, out);
}